// Round 3
// baseline (757.653 us; speedup 1.0000x reference)
//
#include <hip/hip_runtime.h>
#include <hip/hip_bf16.h>

#define N_NODES 100000
#define N_EDGES 1600000
#define DIM 64
#define NBUCK 782        // ceil(N_NODES / 128), bucket = col >> 7
#define BK_NODES 128
#define HA_EPB 16384     // edges per block in histA / scatterA
#define HA_BLOCKS 98     // ceil(N_EDGES / HA_EPB)

// ---------------------------------------------------------------------------
// 1) zero bucket counts
// ---------------------------------------------------------------------------
__global__ __launch_bounds__(1024) void zeroA_kernel(int* __restrict__ bcnt) {
    int i = threadIdx.x;
    if (i < NBUCK) bcnt[i] = 0;
}

// ---------------------------------------------------------------------------
// 2) bucket histogram: LDS-aggregated, ~77K global atomics total
// ---------------------------------------------------------------------------
__global__ __launch_bounds__(1024) void histA_kernel(const int* __restrict__ col,
                                                     int* __restrict__ bcnt) {
    __shared__ int h[NBUCK];
    for (int i = threadIdx.x; i < NBUCK; i += 1024) h[i] = 0;
    __syncthreads();
    int bstart = blockIdx.x * HA_EPB;
    int bend = bstart + HA_EPB;
    if (bend > N_EDGES) bend = N_EDGES;
    for (int e = bstart + threadIdx.x; e < bend; e += 1024)
        atomicAdd(&h[col[e] >> 7], 1);
    __syncthreads();
    for (int i = threadIdx.x; i < NBUCK; i += 1024)
        if (h[i]) atomicAdd(&bcnt[i], h[i]);
}

// ---------------------------------------------------------------------------
// 3) exclusive scan of 782 bucket counts -> boff, bcur
// ---------------------------------------------------------------------------
__global__ __launch_bounds__(1024) void scanA_kernel(const int* __restrict__ bcnt,
                                                     int* __restrict__ boff,
                                                     int* __restrict__ bcur) {
    __shared__ int tmp[1024];
    int tid = threadIdx.x;
    int v = (tid < NBUCK) ? bcnt[tid] : 0;
    tmp[tid] = v;
    __syncthreads();
    for (int off = 1; off < 1024; off <<= 1) {
        int t = (tid >= off) ? tmp[tid - off] : 0;
        __syncthreads();
        tmp[tid] += t;
        __syncthreads();
    }
    if (tid < NBUCK) {
        int ex = tmp[tid] - v;
        boff[tid] = ex;
        bcur[tid] = ex;
    }
    if (tid == 0) boff[NBUCK] = N_EDGES;
}

// ---------------------------------------------------------------------------
// 4) bucket scatter: per-block LDS hist -> reserve range -> write packed
//    (row<<7 | local_col). Writes are ~contiguous chunks per bucket.
// ---------------------------------------------------------------------------
__global__ __launch_bounds__(1024) void scatterA_kernel(const int* __restrict__ row,
                                                        const int* __restrict__ col,
                                                        int* __restrict__ bcur,
                                                        int* __restrict__ pairs) {
    __shared__ int h[NBUCK];
    __shared__ int base[NBUCK];
    for (int i = threadIdx.x; i < NBUCK; i += 1024) h[i] = 0;
    __syncthreads();
    int bstart = blockIdx.x * HA_EPB;
    int bend = bstart + HA_EPB;
    if (bend > N_EDGES) bend = N_EDGES;
    for (int e = bstart + threadIdx.x; e < bend; e += 1024)
        atomicAdd(&h[col[e] >> 7], 1);
    __syncthreads();
    for (int i = threadIdx.x; i < NBUCK; i += 1024) {
        int c = h[i];
        base[i] = c ? atomicAdd(&bcur[i], c) : 0;
        h[i] = 0;  // reuse as local cursor
    }
    __syncthreads();
    for (int e = bstart + threadIdx.x; e < bend; e += 1024) {
        int c = col[e];
        int bk = c >> 7;
        int pos = base[bk] + atomicAdd(&h[bk], 1);
        pairs[pos] = (row[e] << 7) | (c & 127);
    }
}

// ---------------------------------------------------------------------------
// 5) per-bucket degree -> dinv = rsqrt(deg + 1)
// ---------------------------------------------------------------------------
__global__ __launch_bounds__(256) void countB_kernel(const int* __restrict__ boff,
                                                     const int* __restrict__ pairs,
                                                     float* __restrict__ dinv) {
    __shared__ int cnt[BK_NODES];
    int b = blockIdx.x;
    if (threadIdx.x < BK_NODES) cnt[threadIdx.x] = 0;
    __syncthreads();
    int s0 = boff[b], e0 = boff[b + 1];
    for (int p = s0 + threadIdx.x; p < e0; p += 256)
        atomicAdd(&cnt[pairs[p] & 127], 1);
    __syncthreads();
    int node = b * BK_NODES + threadIdx.x;
    if (threadIdx.x < BK_NODES && node < N_NODES)
        dinv[node] = rsqrtf((float)(cnt[threadIdx.x] + 1));
}

// ---------------------------------------------------------------------------
// 6) s[n][j] = dinv[n] * sum_k x[n][k] * W[j][k]
//    lane j caches W-row j in 64 VGPRs; n forced wave-uniform so x-row
//    reads become scalar loads; inner loop = 64 pure v_fma.
// ---------------------------------------------------------------------------
__global__ __launch_bounds__(256) void gemm_kernel(const float* __restrict__ x,
                                                   const float* __restrict__ W,
                                                   const float* __restrict__ dinv,
                                                   float* __restrict__ s) {
    const int wave = threadIdx.x >> 6;
    const int lane = threadIdx.x & 63;
    float w[DIM];
#pragma unroll
    for (int k = 0; k < DIM; k += 4) {
        float4 t = *(const float4*)&W[lane * DIM + k];
        w[k] = t.x; w[k + 1] = t.y; w[k + 2] = t.z; w[k + 3] = t.w;
    }
    const int waves_total = gridDim.x * 4;
    for (int n0 = blockIdx.x * 4 + wave; n0 < N_NODES; n0 += waves_total) {
        int n = __builtin_amdgcn_readfirstlane(n0);
        float acc = 0.0f;
#pragma unroll
        for (int k = 0; k < DIM; ++k)
            acc = fmaf(x[n * DIM + k], w[k], acc);
        s[(size_t)n * DIM + lane] = acc * dinv[n];
    }
}

// ---------------------------------------------------------------------------
// 7) fused aggregate + finalize: block-per-bucket, 32KB LDS accumulator,
//    ds_add_f32 accumulation (no global atomics), contiguous 32KB write.
// ---------------------------------------------------------------------------
__global__ __launch_bounds__(512) void agg_kernel(const int* __restrict__ boff,
                                                  const int* __restrict__ pairs,
                                                  const float* __restrict__ s,
                                                  const float* __restrict__ dinv,
                                                  const float* __restrict__ bias,
                                                  float* __restrict__ out) {
    __shared__ float acc[BK_NODES * DIM];  // 32 KB
    int b = blockIdx.x;
    for (int i = threadIdx.x; i < BK_NODES * DIM; i += 512) acc[i] = 0.0f;
    __syncthreads();

    int s0 = boff[b], e0 = boff[b + 1];
    int wave = threadIdx.x >> 6;
    int lane = threadIdx.x & 63;

    int pp = s0 + wave;
    for (; pp + 8 < e0; pp += 16) {
        int pk0 = pairs[pp];
        int pk1 = pairs[pp + 8];
        float v0 = s[(size_t)(pk0 >> 7) * DIM + lane];
        float v1 = s[(size_t)(pk1 >> 7) * DIM + lane];
        atomicAdd(&acc[(pk0 & 127) * DIM + lane], v0);
        atomicAdd(&acc[(pk1 & 127) * DIM + lane], v1);
    }
    for (; pp < e0; pp += 8) {
        int pk = pairs[pp];
        atomicAdd(&acc[(pk & 127) * DIM + lane], s[(size_t)(pk >> 7) * DIM + lane]);
    }
    __syncthreads();

    for (int i = threadIdx.x; i < BK_NODES * DIM; i += 512) {
        int local = i >> 6, j = i & 63;
        int node = b * BK_NODES + local;
        if (node < N_NODES) {
            float a = acc[i] + s[(size_t)node * DIM + j];  // + self-loop term
            out[(size_t)node * DIM + j] = fmaxf(fmaf(dinv[node], a, bias[j]), 0.0f);
        }
    }
}

extern "C" void kernel_launch(void* const* d_in, const int* in_sizes, int n_in,
                              void* d_out, int out_size, void* d_ws, size_t ws_size,
                              hipStream_t stream) {
    const float* x    = (const float*)d_in[0];
    const int*   ei   = (const int*)d_in[1];  // [2, E] int32
    const float* W    = (const float*)d_in[2];
    const float* bias = (const float*)d_in[3];
    float*       out  = (float*)d_out;

    const int* row = ei;            // source nodes
    const int* col = ei + N_EDGES;  // target nodes

    // workspace layout (bytes):
    //   bcnt   int[1024]        @ 0
    //   boff   int[1024]        @ 4096
    //   bcur   int[1024]        @ 8192
    //   dinv   float[100000]    @ 12288    (400000 B)
    //   pairs  int[1600000]     @ 413696   (6400000 B)
    //   s      float[6400000]   @ 6813952  (25600000 B)  -> end ~32.4 MB
    char* ws = (char*)d_ws;
    int*   bcnt  = (int*)(ws + 0);
    int*   boff  = (int*)(ws + 4096);
    int*   bcur  = (int*)(ws + 8192);
    float* dinv  = (float*)(ws + 12288);
    int*   pairs = (int*)(ws + 413696);
    float* s     = (float*)(ws + 6813952);

    zeroA_kernel<<<1, 1024, 0, stream>>>(bcnt);
    histA_kernel<<<HA_BLOCKS, 1024, 0, stream>>>(col, bcnt);
    scanA_kernel<<<1, 1024, 0, stream>>>(bcnt, boff, bcur);
    scatterA_kernel<<<HA_BLOCKS, 1024, 0, stream>>>(row, col, bcur, pairs);
    countB_kernel<<<NBUCK, 256, 0, stream>>>(boff, pairs, dinv);
    gemm_kernel<<<2048, 256, 0, stream>>>(x, W, dinv, s);
    agg_kernel<<<NBUCK, 512, 0, stream>>>(boff, pairs, s, dinv, bias, out);
}

// Round 4
// 147.346 us; speedup vs baseline: 5.1420x; 5.1420x over previous
//
#include <hip/hip_runtime.h>
#include <hip/hip_bf16.h>

#define N_NODES 100000
#define N_EDGES 1600000
#define DIM 64
#define NBUCK 782        // ceil(N_NODES / 128), bucket = col >> 7
#define BK_NODES 128
#define HA_EPB 16384     // edges per block in histA / scatterA
#define HA_BLOCKS 98     // ceil(N_EDGES / HA_EPB)

typedef unsigned int uint32;

// bf16 (as u16 pair packed in u32) -> float helpers
__device__ __forceinline__ float bflo(uint32 u) { return __uint_as_float(u << 16); }
__device__ __forceinline__ float bfhi(uint32 u) { return __uint_as_float(u & 0xffff0000u); }

// ---------------------------------------------------------------------------
// 1) zero bucket counts
// ---------------------------------------------------------------------------
__global__ __launch_bounds__(1024) void zeroA_kernel(int* __restrict__ bcnt) {
    int i = threadIdx.x;
    if (i < NBUCK) bcnt[i] = 0;
}

// ---------------------------------------------------------------------------
// 2) bucket histogram: LDS-aggregated
// ---------------------------------------------------------------------------
__global__ __launch_bounds__(1024) void histA_kernel(const int* __restrict__ col,
                                                     int* __restrict__ bcnt) {
    __shared__ int h[NBUCK];
    for (int i = threadIdx.x; i < NBUCK; i += 1024) h[i] = 0;
    __syncthreads();
    int bstart = blockIdx.x * HA_EPB;
    int bend = bstart + HA_EPB;
    if (bend > N_EDGES) bend = N_EDGES;
    for (int e = bstart + threadIdx.x; e < bend; e += 1024)
        atomicAdd(&h[col[e] >> 7], 1);
    __syncthreads();
    for (int i = threadIdx.x; i < NBUCK; i += 1024)
        if (h[i]) atomicAdd(&bcnt[i], h[i]);
}

// ---------------------------------------------------------------------------
// 3) exclusive scan of 782 bucket counts -> boff, bcur; set sentinels
// ---------------------------------------------------------------------------
__global__ __launch_bounds__(1024) void scanA_kernel(const int* __restrict__ bcnt,
                                                     int* __restrict__ boff,
                                                     int* __restrict__ bcur,
                                                     int* __restrict__ nodeoff) {
    __shared__ int tmp[1024];
    int tid = threadIdx.x;
    int v = (tid < NBUCK) ? bcnt[tid] : 0;
    tmp[tid] = v;
    __syncthreads();
    for (int off = 1; off < 1024; off <<= 1) {
        int t = (tid >= off) ? tmp[tid - off] : 0;
        __syncthreads();
        tmp[tid] += t;
        __syncthreads();
    }
    if (tid < NBUCK) {
        int ex = tmp[tid] - v;
        boff[tid] = ex;
        bcur[tid] = ex;
    }
    if (tid == 0) {
        boff[NBUCK] = N_EDGES;
        nodeoff[N_NODES] = N_EDGES;
    }
}

// ---------------------------------------------------------------------------
// 4) bucket scatter: per-block LDS hist -> reserve range -> write packed
//    (row<<7 | local_col). Writes land in 782 contiguous regions.
// ---------------------------------------------------------------------------
__global__ __launch_bounds__(1024) void scatterA_kernel(const int* __restrict__ row,
                                                        const int* __restrict__ col,
                                                        int* __restrict__ bcur,
                                                        int* __restrict__ pairs) {
    __shared__ int h[NBUCK];
    __shared__ int base[NBUCK];
    for (int i = threadIdx.x; i < NBUCK; i += 1024) h[i] = 0;
    __syncthreads();
    int bstart = blockIdx.x * HA_EPB;
    int bend = bstart + HA_EPB;
    if (bend > N_EDGES) bend = N_EDGES;
    for (int e = bstart + threadIdx.x; e < bend; e += 1024)
        atomicAdd(&h[col[e] >> 7], 1);
    __syncthreads();
    for (int i = threadIdx.x; i < NBUCK; i += 1024) {
        int c = h[i];
        base[i] = c ? atomicAdd(&bcur[i], c) : 0;
        h[i] = 0;  // reuse as local cursor
    }
    __syncthreads();
    for (int e = bstart + threadIdx.x; e < bend; e += 1024) {
        int c = col[e];
        int bk = c >> 7;
        int pos = base[bk] + atomicAdd(&h[bk], 1);
        pairs[pos] = (row[e] << 7) | (c & 127);
    }
}

// ---------------------------------------------------------------------------
// 5) per-bucket: count per node, scan -> per-node CSR offsets + dinv,
//    then within-bucket sort: srow grouped by destination node.
//    All global writes are contiguous or within the bucket's 8KB region.
// ---------------------------------------------------------------------------
__global__ __launch_bounds__(256) void sortB_kernel(const int* __restrict__ boff,
                                                    const int* __restrict__ pairs,
                                                    int* __restrict__ srow,
                                                    int* __restrict__ nodeoff,
                                                    float* __restrict__ dinv) {
    __shared__ int cnt[BK_NODES];
    __shared__ int sc[BK_NODES];
    __shared__ int cur[BK_NODES];
    int b = blockIdx.x;
    int tid = threadIdx.x;
    if (tid < BK_NODES) cnt[tid] = 0;
    __syncthreads();
    int s0 = boff[b], e0 = boff[b + 1];
    for (int p = s0 + tid; p < e0; p += 256)
        atomicAdd(&cnt[pairs[p] & 127], 1);
    __syncthreads();
    if (tid < BK_NODES) sc[tid] = cnt[tid];
    __syncthreads();
    for (int off = 1; off < BK_NODES; off <<= 1) {
        int t = 0;
        if (tid < BK_NODES && tid >= off) t = sc[tid - off];
        __syncthreads();
        if (tid < BK_NODES) sc[tid] += t;
        __syncthreads();
    }
    if (tid < BK_NODES) {
        int ex = sc[tid] - cnt[tid];  // exclusive
        int node = b * BK_NODES + tid;
        cur[tid] = s0 + ex;
        if (node < N_NODES) {
            nodeoff[node] = s0 + ex;
            dinv[node] = rsqrtf((float)(cnt[tid] + 1));  // +1 self-loop
        }
    }
    __syncthreads();
    for (int p = s0 + tid; p < e0; p += 256) {
        int pk = pairs[p];
        int pos = atomicAdd(&cur[pk & 127], 1);
        srow[pos] = pk >> 7;
    }
}

// ---------------------------------------------------------------------------
// 6) s[n][j] = bf16( dinv[n] * sum_k x[n][k] * W[j][k] )
//    lane j caches W-row j in VGPRs; n wave-uniform -> x reads are scalar.
// ---------------------------------------------------------------------------
__global__ __launch_bounds__(256) void gemm_kernel(const float* __restrict__ x,
                                                   const float* __restrict__ W,
                                                   const float* __restrict__ dinv,
                                                   __hip_bfloat16* __restrict__ sb) {
    const int wave = threadIdx.x >> 6;
    const int lane = threadIdx.x & 63;
    float w[DIM];
#pragma unroll
    for (int k = 0; k < DIM; k += 4) {
        float4 t = *(const float4*)&W[lane * DIM + k];
        w[k] = t.x; w[k + 1] = t.y; w[k + 2] = t.z; w[k + 3] = t.w;
    }
    const int waves_total = gridDim.x * 4;
    for (int n0 = blockIdx.x * 4 + wave; n0 < N_NODES; n0 += waves_total) {
        int n = __builtin_amdgcn_readfirstlane(n0);
        float acc = 0.0f;
#pragma unroll
        for (int k = 0; k < DIM; ++k)
            acc = fmaf(x[n * DIM + k], w[k], acc);
        sb[(size_t)n * DIM + lane] = __float2bfloat16(acc * dinv[n]);
    }
}

// ---------------------------------------------------------------------------
// 7) aggregate + finalize: wave-per-node, register accumulation.
//    bf16 rows: 128B per gather, half-wave (32 lanes) per edge ->
//    2 edges concurrent per wave, 8-deep unroll -> 16 gathers in flight.
// ---------------------------------------------------------------------------
__global__ __launch_bounds__(256) void agg_kernel(const int* __restrict__ nodeoff,
                                                  const int* __restrict__ srow,
                                                  const uint32* __restrict__ s2,
                                                  const float* __restrict__ dinv,
                                                  const float* __restrict__ bias,
                                                  float* __restrict__ out) {
    int n = __builtin_amdgcn_readfirstlane(blockIdx.x * 4 + (threadIdx.x >> 6));
    if (n >= N_NODES) return;
    int lane = threadIdx.x & 63;
    int half = lane >> 5;
    int l = lane & 31;

    int start = nodeoff[n];
    int end = nodeoff[n + 1];

    float a0 = 0.0f, a1 = 0.0f;
    int p = start + half;  // halves interleave over edges
    for (; p + 14 < end; p += 16) {
        int r0 = srow[p];
        int r1 = srow[p + 2];
        int r2 = srow[p + 4];
        int r3 = srow[p + 6];
        int r4 = srow[p + 8];
        int r5 = srow[p + 10];
        int r6 = srow[p + 12];
        int r7 = srow[p + 14];
        uint32 u0 = s2[(size_t)r0 * 32 + l];
        uint32 u1 = s2[(size_t)r1 * 32 + l];
        uint32 u2 = s2[(size_t)r2 * 32 + l];
        uint32 u3 = s2[(size_t)r3 * 32 + l];
        uint32 u4 = s2[(size_t)r4 * 32 + l];
        uint32 u5 = s2[(size_t)r5 * 32 + l];
        uint32 u6 = s2[(size_t)r6 * 32 + l];
        uint32 u7 = s2[(size_t)r7 * 32 + l];
        a0 += bflo(u0); a1 += bfhi(u0);
        a0 += bflo(u1); a1 += bfhi(u1);
        a0 += bflo(u2); a1 += bfhi(u2);
        a0 += bflo(u3); a1 += bfhi(u3);
        a0 += bflo(u4); a1 += bfhi(u4);
        a0 += bflo(u5); a1 += bfhi(u5);
        a0 += bflo(u6); a1 += bfhi(u6);
        a0 += bflo(u7); a1 += bfhi(u7);
    }
    for (; p < end; p += 2) {
        uint32 u = s2[(size_t)srow[p] * 32 + l];
        a0 += bflo(u); a1 += bfhi(u);
    }

    // merge the two half-wave partial sums (lane l += lane l+32)
    a0 += __shfl_xor(a0, 32);
    a1 += __shfl_xor(a1, 32);

    if (half == 0) {
        uint32 us = s2[(size_t)n * 32 + l];  // self-loop term
        a0 += bflo(us);
        a1 += bfhi(us);
        float2 bb = *(const float2*)&bias[2 * l];
        float d = dinv[n];
        float o0 = fmaxf(fmaf(d, a0, bb.x), 0.0f);
        float o1 = fmaxf(fmaf(d, a1, bb.y), 0.0f);
        *(float2*)&out[(size_t)n * DIM + 2 * l] = make_float2(o0, o1);
    }
}

extern "C" void kernel_launch(void* const* d_in, const int* in_sizes, int n_in,
                              void* d_out, int out_size, void* d_ws, size_t ws_size,
                              hipStream_t stream) {
    const float* x    = (const float*)d_in[0];
    const int*   ei   = (const int*)d_in[1];  // [2, E] int32
    const float* W    = (const float*)d_in[2];
    const float* bias = (const float*)d_in[3];
    float*       out  = (float*)d_out;

    const int* row = ei;            // source nodes
    const int* col = ei + N_EDGES;  // target nodes

    // workspace layout (bytes, 128-aligned):
    //   bcnt    int[1024]           @ 0
    //   boff    int[1024]           @ 4096
    //   bcur    int[1024]           @ 8192
    //   dinv    float[100000]       @ 12288     (400000)
    //   nodeoff int[100001]         @ 412416    (400004)
    //   pairs   int[1600000]        @ 812544    (6400000)
    //   srow    int[1600000]        @ 7212544   (6400000)
    //   sb      bf16[6400000]       @ 13612544  (12800000) -> end ~26.4 MB
    char* ws = (char*)d_ws;
    int*            bcnt    = (int*)(ws + 0);
    int*            boff    = (int*)(ws + 4096);
    int*            bcur    = (int*)(ws + 8192);
    float*          dinv    = (float*)(ws + 12288);
    int*            nodeoff = (int*)(ws + 412416);
    int*            pairs   = (int*)(ws + 812544);
    int*            srow    = (int*)(ws + 7212544);
    __hip_bfloat16* sb      = (__hip_bfloat16*)(ws + 13612544);

    zeroA_kernel<<<1, 1024, 0, stream>>>(bcnt);
    histA_kernel<<<HA_BLOCKS, 1024, 0, stream>>>(col, bcnt);
    scanA_kernel<<<1, 1024, 0, stream>>>(bcnt, boff, bcur, nodeoff);
    scatterA_kernel<<<HA_BLOCKS, 1024, 0, stream>>>(row, col, bcur, pairs);
    sortB_kernel<<<NBUCK, 256, 0, stream>>>(boff, pairs, srow, nodeoff, dinv);
    gemm_kernel<<<2048, 256, 0, stream>>>(x, W, dinv, sb);
    agg_kernel<<<(N_NODES + 3) / 4, 256, 0, stream>>>(nodeoff, srow, (const uint32*)sb,
                                                      dinv, bias, out);
}

// Round 5
// 120.014 us; speedup vs baseline: 6.3131x; 1.2277x over previous
//
#include <hip/hip_runtime.h>
#include <hip/hip_bf16.h>

#define N_NODES 100000
#define N_EDGES 1600000
#define DIM 64
#define NBUCK 782        // ceil(N_NODES / 128), bucket = col >> 7
#define BK_NODES 128
#define CAP 2560         // slots per bucket (mean 2048, sigma ~45 -> >11 sigma)
#define HA_EPB 16384     // edges per block in scatter
#define HA_BLOCKS 98     // ceil(N_EDGES / HA_EPB)

typedef unsigned int uint32;

// bf16 (u16 pair packed in u32) -> float helpers
__device__ __forceinline__ float bflo(uint32 u) { return __uint_as_float(u << 16); }
__device__ __forceinline__ float bfhi(uint32 u) { return __uint_as_float(u & 0xffff0000u); }

// ---------------------------------------------------------------------------
// 1) zero the bucket counters (tiny)
// ---------------------------------------------------------------------------
__global__ __launch_bounds__(1024) void zero_kernel(int* __restrict__ bcnt) {
    if (threadIdx.x < NBUCK) bcnt[threadIdx.x] = 0;
}

// ---------------------------------------------------------------------------
// 2) single-pass bucket scatter: edges cached in registers, LDS hist,
//    one global atomic per (block,bucket) reservation, packed write into
//    fixed-capacity bucket region pairs[bk*CAP ...].
// ---------------------------------------------------------------------------
__global__ __launch_bounds__(1024) void scatter_kernel(const int* __restrict__ row,
                                                       const int* __restrict__ col,
                                                       int* __restrict__ bcnt,
                                                       int* __restrict__ pairs) {
    __shared__ int h[NBUCK];
    __shared__ int base[NBUCK];
    for (int i = threadIdx.x; i < NBUCK; i += 1024) h[i] = 0;
    __syncthreads();

    const int bstart = blockIdx.x * HA_EPB;
    int r[16], c[16];
#pragma unroll 16
    for (int k = 0; k < 16; ++k) {
        int e = bstart + threadIdx.x + k * 1024;
        if (e < N_EDGES) {
            r[k] = row[e];
            c[k] = col[e];
            atomicAdd(&h[c[k] >> 7], 1);
        }
    }
    __syncthreads();
    for (int i = threadIdx.x; i < NBUCK; i += 1024) {
        int v = h[i];
        base[i] = v ? atomicAdd(&bcnt[i], v) : 0;
        h[i] = 0;  // reuse as local cursor
    }
    __syncthreads();
#pragma unroll 16
    for (int k = 0; k < 16; ++k) {
        int e = bstart + threadIdx.x + k * 1024;
        if (e < N_EDGES) {
            int bk = c[k] >> 7;
            int pos = base[bk] + atomicAdd(&h[bk], 1);
            if (pos < CAP) pairs[bk * CAP + pos] = (r[k] << 7) | (c[k] & 127);
        }
    }
}

// ---------------------------------------------------------------------------
// 3) per-bucket in-place sort: stage bucket in LDS, per-node count + scan,
//    overwrite bucket region with row indices grouped by destination node.
//    Emits packed CSR metadata info[n] = (start<<8)|deg and dinv[n].
// ---------------------------------------------------------------------------
__global__ __launch_bounds__(256) void sort_kernel(const int* __restrict__ bcnt,
                                                   int* __restrict__ pairs,
                                                   int* __restrict__ info,
                                                   float* __restrict__ dinv) {
    __shared__ int cnt[BK_NODES];
    __shared__ int sc[BK_NODES];
    __shared__ int cur[BK_NODES];
    __shared__ int buf[CAP];
    const int b = blockIdx.x;
    const int tid = threadIdx.x;
    const int n = bcnt[b];
    if (tid < BK_NODES) cnt[tid] = 0;
    __syncthreads();
    for (int p = tid; p < n; p += 256) {
        int pk = pairs[b * CAP + p];
        buf[p] = pk;
        atomicAdd(&cnt[pk & 127], 1);
    }
    __syncthreads();
    if (tid < BK_NODES) sc[tid] = cnt[tid];
    __syncthreads();
    for (int off = 1; off < BK_NODES; off <<= 1) {
        int t = (tid < BK_NODES && tid >= off) ? sc[tid - off] : 0;
        __syncthreads();
        if (tid < BK_NODES) sc[tid] += t;
        __syncthreads();
    }
    if (tid < BK_NODES) {
        int ex = sc[tid] - cnt[tid];  // exclusive
        cur[tid] = ex;
        int node = b * BK_NODES + tid;
        if (node < N_NODES) {
            info[node] = ((b * CAP + ex) << 8) | cnt[tid];
            dinv[node] = rsqrtf((float)(cnt[tid] + 1));  // +1 self-loop
        }
    }
    __syncthreads();
    for (int p = tid; p < n; p += 256) {
        int pk = buf[p];
        int pos = atomicAdd(&cur[pk & 127], 1);
        pairs[b * CAP + pos] = pk >> 7;  // overwrite: sorted source row index
    }
}

// ---------------------------------------------------------------------------
// 4) s[n][j] = bf16( dinv[n] * sum_k x[n][k] * W[j][k] )
//    lane j caches W-row j in VGPRs; n wave-uniform -> x reads are scalar.
// ---------------------------------------------------------------------------
__global__ __launch_bounds__(256) void gemm_kernel(const float* __restrict__ x,
                                                   const float* __restrict__ W,
                                                   const float* __restrict__ dinv,
                                                   __hip_bfloat16* __restrict__ sb) {
    const int wave = threadIdx.x >> 6;
    const int lane = threadIdx.x & 63;
    float w[DIM];
#pragma unroll
    for (int k = 0; k < DIM; k += 4) {
        float4 t = *(const float4*)&W[lane * DIM + k];
        w[k] = t.x; w[k + 1] = t.y; w[k + 2] = t.z; w[k + 3] = t.w;
    }
    const int waves_total = gridDim.x * 4;
    for (int n0 = blockIdx.x * 4 + wave; n0 < N_NODES; n0 += waves_total) {
        int n = __builtin_amdgcn_readfirstlane(n0);
        float acc = 0.0f;
#pragma unroll
        for (int k = 0; k < DIM; ++k)
            acc = fmaf(x[n * DIM + k], w[k], acc);
        sb[(size_t)n * DIM + lane] = __float2bfloat16(acc * dinv[n]);
    }
}

// ---------------------------------------------------------------------------
// 5) aggregate + finalize: wave-per-node, register accumulation.
//    uint2 (8B) per lane, 16 lanes per 128B row -> 4 edges concurrent per
//    wave instruction, unroll 2 -> 8 gathers in flight.
// ---------------------------------------------------------------------------
__global__ __launch_bounds__(256) void agg_kernel(const int* __restrict__ info,
                                                  const int* __restrict__ srow,
                                                  const uint2* __restrict__ s4,
                                                  const float* __restrict__ dinv,
                                                  const float* __restrict__ bias,
                                                  float* __restrict__ out) {
    int n = __builtin_amdgcn_readfirstlane(blockIdx.x * 4 + (threadIdx.x >> 6));
    if (n >= N_NODES) return;
    const int lane = threadIdx.x & 63;
    const int q = lane >> 4;   // quadrant 0..3: which edge in the group of 4
    const int l = lane & 15;   // 16 lanes x 8B cover one 128B row

    const int iv = info[n];
    const int start = iv >> 8;
    const int end = start + (iv & 255);

    float a0 = 0.0f, a1 = 0.0f, a2 = 0.0f, a3 = 0.0f;
    int p = start + q;
    for (; p + 4 < end; p += 8) {
        int r0 = srow[p];
        int r1 = srow[p + 4];
        uint2 u0 = s4[(size_t)r0 * 16 + l];
        uint2 u1 = s4[(size_t)r1 * 16 + l];
        a0 += bflo(u0.x); a1 += bfhi(u0.x); a2 += bflo(u0.y); a3 += bfhi(u0.y);
        a0 += bflo(u1.x); a1 += bfhi(u1.x); a2 += bflo(u1.y); a3 += bfhi(u1.y);
    }
    if (p < end) {
        int r0 = srow[p];
        uint2 u0 = s4[(size_t)r0 * 16 + l];
        a0 += bflo(u0.x); a1 += bfhi(u0.x); a2 += bflo(u0.y); a3 += bfhi(u0.y);
    }

    // merge quadrants: lanes 0-15 end up with the full sums
    a0 += __shfl_xor(a0, 16); a1 += __shfl_xor(a1, 16);
    a2 += __shfl_xor(a2, 16); a3 += __shfl_xor(a3, 16);
    a0 += __shfl_xor(a0, 32); a1 += __shfl_xor(a1, 32);
    a2 += __shfl_xor(a2, 32); a3 += __shfl_xor(a3, 32);

    if (lane < 16) {
        uint2 us = s4[(size_t)n * 16 + l];  // self-loop term
        a0 += bflo(us.x); a1 += bfhi(us.x);
        a2 += bflo(us.y); a3 += bfhi(us.y);
        float4 bb = *(const float4*)&bias[4 * l];
        float d = dinv[n];
        float4 o;
        o.x = fmaxf(fmaf(d, a0, bb.x), 0.0f);
        o.y = fmaxf(fmaf(d, a1, bb.y), 0.0f);
        o.z = fmaxf(fmaf(d, a2, bb.z), 0.0f);
        o.w = fmaxf(fmaf(d, a3, bb.w), 0.0f);
        *(float4*)&out[(size_t)n * DIM + 4 * l] = o;
    }
}

extern "C" void kernel_launch(void* const* d_in, const int* in_sizes, int n_in,
                              void* d_out, int out_size, void* d_ws, size_t ws_size,
                              hipStream_t stream) {
    const float* x    = (const float*)d_in[0];
    const int*   ei   = (const int*)d_in[1];  // [2, E] int32
    const float* W    = (const float*)d_in[2];
    const float* bias = (const float*)d_in[3];
    float*       out  = (float*)d_out;

    const int* row = ei;            // source nodes
    const int* col = ei + N_EDGES;  // target nodes

    // workspace layout (bytes, 128-aligned):
    //   bcnt  int[1024]            @ 0         (4096)
    //   info  int[100000]          @ 4096      (400000)
    //   dinv  float[100000]        @ 404224    (400000)
    //   pairs int[NBUCK*CAP=2001920] @ 804352  (8007680)  (reused as srow)
    //   sb    bf16[6400000]        @ 8812160   (12800000) -> end ~21.6 MB
    char* ws = (char*)d_ws;
    int*            bcnt  = (int*)(ws + 0);
    int*            info  = (int*)(ws + 4096);
    float*          dinv  = (float*)(ws + 404224);
    int*            pairs = (int*)(ws + 804352);
    __hip_bfloat16* sb    = (__hip_bfloat16*)(ws + 8812160);

    zero_kernel<<<1, 1024, 0, stream>>>(bcnt);
    scatter_kernel<<<HA_BLOCKS, 1024, 0, stream>>>(row, col, bcnt, pairs);
    sort_kernel<<<NBUCK, 256, 0, stream>>>(bcnt, pairs, info, dinv);
    gemm_kernel<<<2048, 256, 0, stream>>>(x, W, dinv, sb);
    agg_kernel<<<(N_NODES + 3) / 4, 256, 0, stream>>>(info, pairs, (const uint2*)sb,
                                                      dinv, bias, out);
}

// Round 6
// 94.574 us; speedup vs baseline: 8.0112x; 1.2690x over previous
//
#include <hip/hip_runtime.h>
#include <hip/hip_bf16.h>

#define N_NODES 100000
#define N_EDGES 1600000
#define DIM 64
#define NBUCK 782        // ceil(N_NODES / 128), bucket = col >> 7
#define BK_NODES 128
#define CAP 2560         // slots per bucket (mean 2048, sigma ~45 -> >11 sigma)
#define HA_EPB 16384     // edges per block in scatter
#define HA_BLOCKS 98     // ceil(N_EDGES / HA_EPB)

typedef unsigned int uint32;
typedef __attribute__((ext_vector_type(8))) short bf16x8;
typedef __attribute__((ext_vector_type(4))) float f32x4;

// bf16 (u16 pair packed in u32) -> float helpers
__device__ __forceinline__ float bflo(uint32 u) { return __uint_as_float(u << 16); }
__device__ __forceinline__ float bfhi(uint32 u) { return __uint_as_float(u & 0xffff0000u); }

__device__ __forceinline__ short f2bf(float f) {
    __hip_bfloat16 h = __float2bfloat16(f);
    return (short)__builtin_bit_cast(unsigned short, h);
}
__device__ __forceinline__ uint32 pack2bf(float lo, float hi) {
    unsigned short a = __builtin_bit_cast(unsigned short, __float2bfloat16(lo));
    unsigned short b = __builtin_bit_cast(unsigned short, __float2bfloat16(hi));
    return ((uint32)b << 16) | (uint32)a;
}

// ---------------------------------------------------------------------------
// 1) zero the bucket counters (tiny)
// ---------------------------------------------------------------------------
__global__ __launch_bounds__(1024) void zero_kernel(int* __restrict__ bcnt) {
    if (threadIdx.x < NBUCK) bcnt[threadIdx.x] = 0;
}

// ---------------------------------------------------------------------------
// 2) single-pass bucket scatter (unchanged from round 5)
// ---------------------------------------------------------------------------
__global__ __launch_bounds__(1024) void scatter_kernel(const int* __restrict__ row,
                                                       const int* __restrict__ col,
                                                       int* __restrict__ bcnt,
                                                       int* __restrict__ pairs) {
    __shared__ int h[NBUCK];
    __shared__ int base[NBUCK];
    for (int i = threadIdx.x; i < NBUCK; i += 1024) h[i] = 0;
    __syncthreads();

    const int bstart = blockIdx.x * HA_EPB;
    int r[16], c[16];
#pragma unroll 16
    for (int k = 0; k < 16; ++k) {
        int e = bstart + threadIdx.x + k * 1024;
        if (e < N_EDGES) {
            r[k] = row[e];
            c[k] = col[e];
            atomicAdd(&h[c[k] >> 7], 1);
        }
    }
    __syncthreads();
    for (int i = threadIdx.x; i < NBUCK; i += 1024) {
        int v = h[i];
        base[i] = v ? atomicAdd(&bcnt[i], v) : 0;
        h[i] = 0;  // reuse as local cursor
    }
    __syncthreads();
#pragma unroll 16
    for (int k = 0; k < 16; ++k) {
        int e = bstart + threadIdx.x + k * 1024;
        if (e < N_EDGES) {
            int bk = c[k] >> 7;
            int pos = base[bk] + atomicAdd(&h[bk], 1);
            if (pos < CAP) pairs[bk * CAP + pos] = (r[k] << 7) | (c[k] & 127);
        }
    }
}

// ---------------------------------------------------------------------------
// 3) per-bucket in-place sort (unchanged from round 5)
// ---------------------------------------------------------------------------
__global__ __launch_bounds__(256) void sort_kernel(const int* __restrict__ bcnt,
                                                   int* __restrict__ pairs,
                                                   int* __restrict__ info,
                                                   float* __restrict__ dinv) {
    __shared__ int cnt[BK_NODES];
    __shared__ int sc[BK_NODES];
    __shared__ int cur[BK_NODES];
    __shared__ int buf[CAP];
    const int b = blockIdx.x;
    const int tid = threadIdx.x;
    const int n = bcnt[b];
    if (tid < BK_NODES) cnt[tid] = 0;
    __syncthreads();
    for (int p = tid; p < n; p += 256) {
        int pk = pairs[b * CAP + p];
        buf[p] = pk;
        atomicAdd(&cnt[pk & 127], 1);
    }
    __syncthreads();
    if (tid < BK_NODES) sc[tid] = cnt[tid];
    __syncthreads();
    for (int off = 1; off < BK_NODES; off <<= 1) {
        int t = (tid < BK_NODES && tid >= off) ? sc[tid - off] : 0;
        __syncthreads();
        if (tid < BK_NODES) sc[tid] += t;
        __syncthreads();
    }
    if (tid < BK_NODES) {
        int ex = sc[tid] - cnt[tid];  // exclusive
        cur[tid] = ex;
        int node = b * BK_NODES + tid;
        if (node < N_NODES) {
            info[node] = ((b * CAP + ex) << 8) | cnt[tid];
            dinv[node] = rsqrtf((float)(cnt[tid] + 1));  // +1 self-loop
        }
    }
    __syncthreads();
    for (int p = tid; p < n; p += 256) {
        int pk = buf[p];
        int pos = atomicAdd(&cur[pk & 127], 1);
        pairs[b * CAP + pos] = pk >> 7;  // overwrite: sorted source row index
    }
}

// ---------------------------------------------------------------------------
// 4) MFMA GEMM: sb[n][j] = bf16(dinv[n] * sum_k x[n][k] * W[j][k])
//    4 waves x 16-row tiles per block (64 rows/block).
//    A = x rows (bf16), B = W^T (lane reads W row j contiguously).
//    Output staged in LDS, packed to bf16, coalesced dwordx4 stores.
// ---------------------------------------------------------------------------
__global__ __launch_bounds__(256) void gemm_kernel(const float* __restrict__ x,
                                                   const float* __restrict__ W,
                                                   const float* __restrict__ dinv,
                                                   uint32* __restrict__ sbw) {
    __shared__ float lds[64 * 64];  // 16 KB f32 staging
    const int wave = threadIdx.x >> 6;
    const int lane = threadIdx.x & 63;
    const int base = blockIdx.x * 64;
    const int r16 = lane & 15;   // A: row in tile; B: col j in tile
    const int kb = lane >> 4;    // k-block (8 elems each)

    // B fragments: wb[t][h] holds W[(r16+16t)][kb*8 + 32h + 0..7] as bf16x8
    bf16x8 wb[4][2];
#pragma unroll
    for (int t = 0; t < 4; ++t) {
#pragma unroll
        for (int h = 0; h < 2; ++h) {
            const float* wp = &W[(r16 + 16 * t) * DIM + 32 * h + kb * 8];
            float4 p0 = *(const float4*)wp;
            float4 p1 = *(const float4*)(wp + 4);
            bf16x8 f;
            f[0] = f2bf(p0.x); f[1] = f2bf(p0.y); f[2] = f2bf(p0.z); f[3] = f2bf(p0.w);
            f[4] = f2bf(p1.x); f[5] = f2bf(p1.y); f[6] = f2bf(p1.z); f[7] = f2bf(p1.w);
            wb[t][h] = f;
        }
    }

    // A fragments: x row (clamped), k-slice per kb
    int arow = base + wave * 16 + r16;
    if (arow >= N_NODES) arow = N_NODES - 1;
    bf16x8 af[2];
#pragma unroll
    for (int h = 0; h < 2; ++h) {
        const float* xp = &x[(size_t)arow * DIM + 32 * h + kb * 8];
        float4 p0 = *(const float4*)xp;
        float4 p1 = *(const float4*)(xp + 4);
        bf16x8 f;
        f[0] = f2bf(p0.x); f[1] = f2bf(p0.y); f[2] = f2bf(p0.z); f[3] = f2bf(p0.w);
        f[4] = f2bf(p1.x); f[5] = f2bf(p1.y); f[6] = f2bf(p1.z); f[7] = f2bf(p1.w);
        af[h] = f;
    }

    // dinv for the 4 acc rows this lane owns
    float dv[4];
#pragma unroll
    for (int i = 0; i < 4; ++i) {
        int rr = base + wave * 16 + kb * 4 + i;
        dv[i] = dinv[rr < N_NODES ? rr : N_NODES - 1];
    }

#pragma unroll
    for (int t = 0; t < 4; ++t) {
        f32x4 c = {0.0f, 0.0f, 0.0f, 0.0f};
        c = __builtin_amdgcn_mfma_f32_16x16x32_bf16(af[0], wb[t][0], c, 0, 0, 0);
        c = __builtin_amdgcn_mfma_f32_16x16x32_bf16(af[1], wb[t][1], c, 0, 0, 0);
#pragma unroll
        for (int i = 0; i < 4; ++i)
            lds[(wave * 16 + kb * 4 + i) * 64 + r16 + 16 * t] = c[i] * dv[i];
    }
    __syncthreads();

    // pack + coalesced store: thread t -> row t>>2, 16 cols at (t&3)*16
    int r = threadIdx.x >> 2;
    int cb = threadIdx.x & 3;
    int nrow = base + r;
    if (nrow < N_NODES) {
        const float* src = &lds[r * 64 + cb * 16];
        uint32 o[8];
#pragma unroll
        for (int j = 0; j < 8; ++j) {
            float2 f = *(const float2*)&src[2 * j];
            o[j] = pack2bf(f.x, f.y);
        }
        uint32* dst = sbw + (size_t)nrow * 32 + cb * 8;
        *(uint4*)dst = make_uint4(o[0], o[1], o[2], o[3]);
        *(uint4*)(dst + 4) = make_uint4(o[4], o[5], o[6], o[7]);
    }
}

// ---------------------------------------------------------------------------
// 5) aggregate + finalize: 4 nodes per wave (quarter-wave each), zero
//    shuffles, unroll-4 -> 16 independent gathers in flight per wave.
// ---------------------------------------------------------------------------
__global__ __launch_bounds__(256) void agg_kernel(const int* __restrict__ info,
                                                  const int* __restrict__ srow,
                                                  const uint2* __restrict__ s4,
                                                  const float* __restrict__ dinv,
                                                  const float* __restrict__ bias,
                                                  float* __restrict__ out) {
    const int wid = blockIdx.x * 4 + (threadIdx.x >> 6);
    const int lane = threadIdx.x & 63;
    const int qn = lane >> 4;  // node slot 0..3 within wave
    const int l = lane & 15;   // 16 lanes x 8B = one 128B row

    int n = wid * 4 + qn;
    const bool nvalid = n < N_NODES;
    const int nn = nvalid ? n : N_NODES - 1;
    const int iv = info[nn];
    const int start = iv >> 8;
    const int end = start + (iv & 255);

    float a0 = 0.0f, a1 = 0.0f, a2 = 0.0f, a3 = 0.0f;
    int p = start;
    for (; p + 3 < end; p += 4) {
        int r0 = srow[p], r1 = srow[p + 1], r2 = srow[p + 2], r3 = srow[p + 3];
        uint2 u0 = s4[(size_t)r0 * 16 + l];
        uint2 u1 = s4[(size_t)r1 * 16 + l];
        uint2 u2 = s4[(size_t)r2 * 16 + l];
        uint2 u3 = s4[(size_t)r3 * 16 + l];
        a0 += bflo(u0.x); a1 += bfhi(u0.x); a2 += bflo(u0.y); a3 += bfhi(u0.y);
        a0 += bflo(u1.x); a1 += bfhi(u1.x); a2 += bflo(u1.y); a3 += bfhi(u1.y);
        a0 += bflo(u2.x); a1 += bfhi(u2.x); a2 += bflo(u2.y); a3 += bfhi(u2.y);
        a0 += bflo(u3.x); a1 += bfhi(u3.x); a2 += bflo(u3.y); a3 += bfhi(u3.y);
    }
    int rem = end - p;  // 0..3
    if (rem > 0) {
        int i1 = (rem > 1) ? p + 1 : 0;
        int i2 = (rem > 2) ? p + 2 : 0;
        float m1 = (rem > 1) ? 1.0f : 0.0f;
        float m2 = (rem > 2) ? 1.0f : 0.0f;
        int r0 = srow[p], r1 = srow[i1], r2 = srow[i2];
        uint2 u0 = s4[(size_t)r0 * 16 + l];
        uint2 u1 = s4[(size_t)r1 * 16 + l];
        uint2 u2 = s4[(size_t)r2 * 16 + l];
        a0 += bflo(u0.x); a1 += bfhi(u0.x); a2 += bflo(u0.y); a3 += bfhi(u0.y);
        a0 = fmaf(m1, bflo(u1.x), a0); a1 = fmaf(m1, bfhi(u1.x), a1);
        a2 = fmaf(m1, bflo(u1.y), a2); a3 = fmaf(m1, bfhi(u1.y), a3);
        a0 = fmaf(m2, bflo(u2.x), a0); a1 = fmaf(m2, bfhi(u2.x), a1);
        a2 = fmaf(m2, bflo(u2.y), a2); a3 = fmaf(m2, bfhi(u2.y), a3);
    }

    if (nvalid) {
        uint2 us = s4[(size_t)n * 16 + l];  // self-loop term
        a0 += bflo(us.x); a1 += bfhi(us.x); a2 += bflo(us.y); a3 += bfhi(us.y);
        float4 bb = *(const float4*)&bias[4 * l];
        float d = dinv[n];
        float4 o;
        o.x = fmaxf(fmaf(d, a0, bb.x), 0.0f);
        o.y = fmaxf(fmaf(d, a1, bb.y), 0.0f);
        o.z = fmaxf(fmaf(d, a2, bb.z), 0.0f);
        o.w = fmaxf(fmaf(d, a3, bb.w), 0.0f);
        *(float4*)&out[(size_t)n * DIM + 4 * l] = o;
    }
}

extern "C" void kernel_launch(void* const* d_in, const int* in_sizes, int n_in,
                              void* d_out, int out_size, void* d_ws, size_t ws_size,
                              hipStream_t stream) {
    const float* x    = (const float*)d_in[0];
    const int*   ei   = (const int*)d_in[1];  // [2, E] int32
    const float* W    = (const float*)d_in[2];
    const float* bias = (const float*)d_in[3];
    float*       out  = (float*)d_out;

    const int* row = ei;            // source nodes
    const int* col = ei + N_EDGES;  // target nodes

    // workspace layout (bytes, 128-aligned):
    //   bcnt  int[1024]              @ 0         (4096)
    //   info  int[100000]            @ 4096      (400000)
    //   dinv  float[100000]          @ 404224    (400000)
    //   pairs int[NBUCK*CAP=2001920] @ 804352    (8007680)  (reused as srow)
    //   sb    bf16[6400000]          @ 8812160   (12800000) -> end ~21.6 MB
    char* ws = (char*)d_ws;
    int*    bcnt  = (int*)(ws + 0);
    int*    info  = (int*)(ws + 4096);
    float*  dinv  = (float*)(ws + 404224);
    int*    pairs = (int*)(ws + 804352);
    uint32* sbw   = (uint32*)(ws + 8812160);

    zero_kernel<<<1, 1024, 0, stream>>>(bcnt);
    scatter_kernel<<<HA_BLOCKS, 1024, 0, stream>>>(row, col, bcnt, pairs);
    sort_kernel<<<NBUCK, 256, 0, stream>>>(bcnt, pairs, info, dinv);
    gemm_kernel<<<(N_NODES + 63) / 64, 256, 0, stream>>>(x, W, dinv, sbw);
    agg_kernel<<<(N_NODES + 15) / 16, 256, 0, stream>>>(info, pairs, (const uint2*)sbw,
                                                        dinv, bias, out);
}